// Round 3
// baseline (549.267 us; speedup 1.0000x reference)
//
#include <hip/hip_runtime.h>
#include <cstdint>
#include <cstddef>

#define NS 512
#define NT 384
#define CZ 128

typedef __bf16 bf16x8 __attribute__((ext_vector_type(8)));
typedef __bf16 bf16x4 __attribute__((ext_vector_type(4)));
typedef float floatx16 __attribute__((ext_vector_type(16)));
typedef float floatx4 __attribute__((ext_vector_type(4)));

// Workspace layouts (bf16 element units):
//   A_t[rb(96)][kc(64)][r(128)][e(8)]   panel = 65536 elems (128 rows, k=s)
//   B_t[pb(48)][kc(64)][r(256)][e(8)]   panel = 131072 elems
//   WT [e(128)][k(1024)]  k = (c>>4)*512 + d*16 + (c&15)
// k index = s;  kc = s>>3, e = s&7.  A-row m = i*32+c, B-row n = j*32+d.

// ---------------------------------------------------------------------------
__global__ __launch_bounds__(256) void prep_wout(const float* __restrict__ Wout,
                                                 __bf16* __restrict__ WT) {
  const int idx = blockIdx.x * 256 + threadIdx.x;  // 131072
  const int e = idx >> 10, kk = idx & 1023;
  const int round = kk >> 9, rem = kk & 511, d = rem >> 4, cp = rem & 15;
  const int c = round * 16 + cp;
  WT[idx] = (__bf16)Wout[(size_t)(c * 32 + d) * CZ + e];
}

// ---------------------------------------------------------------------------
__global__ __launch_bounds__(256) void prep_norm(const float* __restrict__ mask,
                                                 float* __restrict__ rnorm) {
  __shared__ float mi[512];
  const int i = blockIdx.x, t = threadIdx.x;
  mi[t]       = mask[(size_t)t * NT + i];
  mi[t + 256] = mask[(size_t)(t + 256) * NT + i];
  __syncthreads();
  for (int j = t; j < NT; j += 256) {
    float acc = 0.f;
#pragma unroll 4
    for (int s = 0; s < NS; ++s) acc += mi[s] * mask[(size_t)s * NT + j];
    rnorm[(size_t)i * NT + j] = 1.0f / (acc + 0.001f);
  }
}

// ---------------------------------------------------------------------------
// LN + projections, writing the tiled layouts. One wave per (i, 64-s chunk).
// LDS: bf16 transpose buffer T aliases the fp32 tile (single-wave block;
// explicit __syncthreads() fences the type-punned overwrite).
// ---------------------------------------------------------------------------
__global__ __launch_bounds__(64) void ln_proj(const float* __restrict__ feat,
                                              const float* __restrict__ mask,
                                              const float* __restrict__ gamma,
                                              const float* __restrict__ beta,
                                              const float* __restrict__ Wa,
                                              const float* __restrict__ Wb,
                                              __bf16* __restrict__ Abf,
                                              __bf16* __restrict__ Bbf) {
  __shared__ __align__(16) float ubuf[64 * 65];    // fp32 tile, row stride 65
  __bf16* T = (__bf16*)ubuf;                       // alias: 32*72 bf16 = 4608 B
  const int bid = blockIdx.x;    // 3072
  const int i = bid >> 3;
  const int s0 = (bid & 7) << 6;
  const int lane = threadIdx.x;
  const int l31 = lane & 31, lh = lane >> 5;

  const int rsub = lane >> 4, cb = (lane & 15) * 4;
#pragma unroll
  for (int rr = 0; rr < 16; ++rr) {
    const int row = rr * 4 + rsub;
    const float4 v = *(const float4*)(feat + ((size_t)(s0 + row) * NT + i) * 64 + cb);
    ubuf[row * 65 + cb] = v.x; ubuf[row * 65 + cb + 1] = v.y;
    ubuf[row * 65 + cb + 2] = v.z; ubuf[row * 65 + cb + 3] = v.w;
  }
  __syncthreads();

  float x[64];
#pragma unroll
  for (int k = 0; k < 64; ++k) x[k] = ubuf[lane * 65 + k];  // lane = s-row

  float mu = 0.f;
#pragma unroll
  for (int k = 0; k < 64; ++k) mu += x[k];
  mu *= (1.0f / 64.0f);
  float var = 0.f;
#pragma unroll
  for (int k = 0; k < 64; ++k) { const float d = x[k] - mu; var += d * d; }
  var *= (1.0f / 64.0f);
  const float rstd = rsqrtf(var + 1e-5f);
#pragma unroll
  for (int k = 0; k < 64; ++k)
    x[k] = (x[k] - mu) * rstd * gamma[k] + beta[k];

  const float mv = mask[(size_t)(s0 + lane) * NT + i];

  // ---- projection A ----
  float acc[32];
#pragma unroll
  for (int c = 0; c < 32; ++c) acc[c] = 0.f;
#pragma unroll 8
  for (int k = 0; k < 64; ++k) {
    const float mk = x[k];
#pragma unroll
    for (int c = 0; c < 32; ++c) acc[c] = fmaf(mk, Wa[k * 32 + c], acc[c]);
  }
  __syncthreads();  // fence: all fp32 tile reads complete before T overwrites it
#pragma unroll
  for (int c = 0; c < 32; ++c) T[c * 72 + lane] = (__bf16)(acc[c] * mv);
  __syncthreads();
  {
    // dest: rb=i>>2, r=(i&3)*32+c, kc = s0/8 + kc_loc, e = s&7
    __bf16* dst = Abf + (size_t)(i >> 2) * 65536 + (size_t)(s0 >> 3) * 1024 +
                  (size_t)((i & 3) * 32) * 8;
#pragma unroll
    for (int q = 0; q < 4; ++q) {
      const bf16x8 v = *(const bf16x8*)(T + l31 * 72 + (q * 2 + lh) * 8);
      *(bf16x8*)(dst + (size_t)(q * 2 + lh) * 1024 + l31 * 8) = v;
    }
  }
  __syncthreads();

  // ---- projection B ----
#pragma unroll
  for (int c = 0; c < 32; ++c) acc[c] = 0.f;
#pragma unroll 8
  for (int k = 0; k < 64; ++k) {
    const float mk = x[k];
#pragma unroll
    for (int c = 0; c < 32; ++c) acc[c] = fmaf(mk, Wb[k * 32 + c], acc[c]);
  }
#pragma unroll
  for (int c = 0; c < 32; ++c) T[c * 72 + lane] = (__bf16)(acc[c] * mv);
  __syncthreads();
  {
    __bf16* dst = Bbf + (size_t)(i >> 3) * 131072 + (size_t)(s0 >> 3) * 2048 +
                  (size_t)((i & 7) * 32) * 8;
#pragma unroll
    for (int q = 0; q < 4; ++q) {
      const bf16x8 v = *(const bf16x8*)(T + l31 * 72 + (q * 2 + lh) * 8);
      *(bf16x8*)(dst + (size_t)(q * 2 + lh) * 2048 + l31 * 8) = v;
    }
  }
}

// ---------------------------------------------------------------------------
// Fused GEMM, occupancy-first geometry (round-2 lesson: kernel is
// latency-bound at 2 waves/SIMD, reg-capped by 128 acc VGPRs).
//   Block 128x128, 4 waves (2x2), wave 64x64 => acc = 2x2x16 = 64 regs,
//   __launch_bounds__(256,4) -> target 4 waves/SIMD (16 waves/CU, 4 blocks).
//   LDS 32 KB: 2 x (A 4kc x 128r x 8e + B 4kc x 128r x 8e) double buffer.
//   Plain __syncthreads double-buffer (counted-vmcnt proved null in r1/r2).
//   Grid 96x96 bm-major: XCD = bm mod 8 -> per-XCD A working set 1.5 MB,
//   L2-resident (this property produced the 115 MB FETCH; keep it).
// Epilogue: 16 (i,j) pairs; P_half[16][516] in LDS (stride 516 -> 2-way max);
// GEMM2 uses mfma_f32_16x16x32_bf16, 4 waves x 32 e-cols, z accumulates
// across the two c-half rounds.
// ---------------------------------------------------------------------------
__global__ __launch_bounds__(256, 4) void opm_gemm(const __bf16* __restrict__ A,
                                                   const __bf16* __restrict__ B,
                                                   const __bf16* __restrict__ WT,
                                                   const float* __restrict__ bout,
                                                   const float* __restrict__ rnorm,
                                                   float* __restrict__ out) {
  __shared__ __align__(16) __bf16 smem[16384];  // 32768 B
  // buffer b: As = smem + b*8192 (4kc x 128 x 8), Bs = As + 4096
  // epilogue alias: P_half[p][kk] at p*516 + kk, p<16, kk<512 (8256 elems)

  const int t = threadIdx.x, lane = t & 63, wid = t >> 6;
  const int wm = wid & 1, wn = wid >> 1;         // 2x2 wave grid
  const int l31 = lane & 31, lh = lane >> 5;
  const int l15 = lane & 15, lq = lane >> 4;     // epilogue 16x16 indexing
  const int bm = blockIdx.x % 96, bn = blockIdx.x / 96;

  const __bf16* Apan = A + (size_t)bm * 65536;
  const __bf16* Bpan = B + (size_t)(bn >> 1) * 131072 + (size_t)(bn & 1) * 1024;

  floatx16 acc[2][2];
#pragma unroll
  for (int fm = 0; fm < 2; ++fm)
#pragma unroll
    for (int fn = 0; fn < 2; ++fn)
#pragma unroll
      for (int q = 0; q < 16; ++q) acc[fm][fn][q] = 0.f;

  // Per kt: A 4096 elems contiguous; B 4 chunks of 1024 elems (kc-strided).
  // 16 x 1KB loads, 4 per wave.
#define STAGE(kt, OFF)                                                          \
  {                                                                             \
    __bf16* dst = smem + (OFF);                                                 \
    _Pragma("unroll")                                                           \
    for (int g2 = 0; g2 < 2; ++g2) {                                            \
      const int g = wid * 2 + g2;                                               \
      __builtin_amdgcn_global_load_lds(                                         \
          (const __attribute__((address_space(1))) void*)(Apan +                \
              (size_t)(kt) * 4096 + g * 512 + lane * 8),                        \
          (__attribute__((address_space(3))) void*)(dst + g * 512), 16, 0, 0);  \
    }                                                                           \
    _Pragma("unroll")                                                           \
    for (int g2 = 0; g2 < 2; ++g2) {                                            \
      const int g = wid * 2 + g2;  /* g = kc*2 + half */                        \
      __builtin_amdgcn_global_load_lds(                                         \
          (const __attribute__((address_space(1))) void*)(Bpan +                \
              (size_t)((kt) * 4 + (g >> 1)) * 2048 + (g & 1) * 512 +            \
              lane * 8),                                                        \
          (__attribute__((address_space(3))) void*)(dst + 4096 + g * 512),      \
          16, 0, 0);                                                            \
    }                                                                           \
  }

  STAGE(0, 0);
  int buf = 0;
  for (int kt = 0; kt < 16; ++kt) {
    __syncthreads();                    // drains stage loads of buf
    if (kt < 15) STAGE(kt + 1, buf ^ 1 ? 8192 : 0);
    const __bf16* As = smem + (buf ? 8192 : 0);
    const __bf16* Bs = As + 4096;
    __builtin_amdgcn_s_setprio(1);
#pragma unroll
    for (int ks = 0; ks < 2; ++ks) {
      const int ck = ks * 2 + lh;
      bf16x8 af[2], bfv[2];
#pragma unroll
      for (int fm = 0; fm < 2; ++fm)
        af[fm] = *(const bf16x8*)(As + ck * 1024 + (wm * 64 + fm * 32 + l31) * 8);
#pragma unroll
      for (int fn = 0; fn < 2; ++fn)
        bfv[fn] = *(const bf16x8*)(Bs + ck * 1024 + (wn * 64 + fn * 32 + l31) * 8);
#pragma unroll
      for (int fm = 0; fm < 2; ++fm)
#pragma unroll
        for (int fn = 0; fn < 2; ++fn)
          acc[fm][fn] = __builtin_amdgcn_mfma_f32_32x32x16_bf16(af[fm], bfv[fn],
                                                                acc[fm][fn], 0, 0, 0);
    }
    __builtin_amdgcn_s_setprio(0);
    buf ^= 1;
  }
#undef STAGE

  // ---- epilogue: 2 rounds over c-halves, z accumulates over rounds ----
  floatx4 zf[2];
#pragma unroll
  for (int ef = 0; ef < 2; ++ef)
#pragma unroll
    for (int q = 0; q < 4; ++q) zf[ef][q] = 0.f;
  const int e0 = wid * 32;

#pragma unroll
  for (int round = 0; round < 2; ++round) {
    __syncthreads();  // main-loop / previous GEMM2 reads complete
    // scatter: p = (wm*2+fm)*4 + (wn*2+fn); P[p][kk], kk = d*16 + (c&15),
    // d = l31, c = 16*round + 8*qp + 4*lh + j  (acc reg = round*8+qp*4+j)
#pragma unroll
    for (int fm = 0; fm < 2; ++fm)
#pragma unroll
      for (int fn = 0; fn < 2; ++fn) {
        const int p = (wm * 2 + fm) * 4 + (wn * 2 + fn);
        __bf16* base = smem + p * 516 + l31 * 16 + lh * 4;
#pragma unroll
        for (int qp = 0; qp < 2; ++qp) {
          bf16x4 v;
#pragma unroll
          for (int j = 0; j < 4; ++j)
            v[j] = (__bf16)acc[fm][fn][round * 8 + qp * 4 + j];
          *(bf16x4*)(base + qp * 8) = v;
        }
      }
    __syncthreads();
    // GEMM2 (16x16x32): z[p][e] += P[p][k] * WT[e][round*512+k], K=512.
    // A-op: lane holds P[l15][kgrp*8..+8]; B-op: lane holds WT[e0+ef*16+l15][...].
    const __bf16* prow = smem + l15 * 516 + lq * 8;
    const __bf16* wrow0 = WT + (size_t)(e0 + l15) * 1024 + round * 512 + lq * 8;
    const __bf16* wrow1 = wrow0 + (size_t)16 * 1024;
#pragma unroll 4
    for (int ks = 0; ks < 16; ++ks) {
      const bf16x8 pa = *(const bf16x8*)(prow + ks * 32);
      const bf16x8 wb0 = *(const bf16x8*)(wrow0 + ks * 32);
      const bf16x8 wb1 = *(const bf16x8*)(wrow1 + ks * 32);
      zf[0] = __builtin_amdgcn_mfma_f32_16x16x32_bf16(pa, wb0, zf[0], 0, 0, 0);
      zf[1] = __builtin_amdgcn_mfma_f32_16x16x32_bf16(pa, wb1, zf[1], 0, 0, 0);
    }
  }

  // out[i][j][e] = (z + bout[e]) * rnorm[i][j]; D-frag: row p = lq*4+q,
  // col e = e0 + ef*16 + l15.
#pragma unroll
  for (int ef = 0; ef < 2; ++ef) {
    const int e = e0 + ef * 16 + l15;
    const float be = bout[e];
#pragma unroll
    for (int q = 0; q < 4; ++q) {
      const int p = lq * 4 + q;
      const int i = bm * 4 + (p >> 2), j = bn * 4 + (p & 3);
      const float rn = rnorm[(size_t)i * NT + j];
      out[((size_t)i * NT + j) * CZ + e] = (zf[ef][q] + be) * rn;
    }
  }
}

// ---------------------------------------------------------------------------
extern "C" void kernel_launch(void* const* d_in, const int* in_sizes, int n_in,
                              void* d_out, int out_size, void* d_ws, size_t ws_size,
                              hipStream_t stream) {
  const float* feat  = (const float*)d_in[0];
  const float* mask  = (const float*)d_in[1];
  const float* gamma = (const float*)d_in[2];
  const float* beta  = (const float*)d_in[3];
  const float* Wa    = (const float*)d_in[4];
  const float* Wb    = (const float*)d_in[5];
  const float* Wout  = (const float*)d_in[6];
  const float* bout  = (const float*)d_in[7];
  float* out = (float*)d_out;

  char* ws = (char*)d_ws;
  const size_t AB_BYTES = (size_t)96 * 65536 * sizeof(__bf16);  // 12,582,912
  __bf16* Abf = (__bf16*)(ws);
  __bf16* Bbf = (__bf16*)(ws + AB_BYTES);
  __bf16* WT  = (__bf16*)(ws + 2 * AB_BYTES);
  float* rnorm = (float*)(ws + 2 * AB_BYTES + (size_t)CZ * 1024 * sizeof(__bf16));

  prep_wout<<<512, 256, 0, stream>>>(Wout, WT);
  prep_norm<<<NT, 256, 0, stream>>>(mask, rnorm);
  ln_proj<<<NT * (NS / 64), 64, 0, stream>>>(feat, mask, gamma, beta, Wa, Wb, Abf, Bbf);
  opm_gemm<<<96 * 96, 256, 0, stream>>>(Abf, Bbf, WT, bout, rnorm, out);
}

// Round 4
// 484.980 us; speedup vs baseline: 1.1326x; 1.1326x over previous
//
#include <hip/hip_runtime.h>
#include <cstdint>
#include <cstddef>

#define NS 512
#define NT 384
#define CZ 128

typedef __bf16 bf16x8 __attribute__((ext_vector_type(8)));
typedef __bf16 bf16x4 __attribute__((ext_vector_type(4)));
typedef float floatx16 __attribute__((ext_vector_type(16)));
typedef float floatx4 __attribute__((ext_vector_type(4)));

// Workspace layouts (bf16 element units):
//   A_t[rb(96)][kc(64)][r(128)][e(8)]   panel = 65536 elems (128 rows, k=s)
//   B_t[pb(48)][kc(64)][r(256)][e(8)]   panel = 131072 elems
//   WT [e(128)][k(1024)]  k = (c>>4)*512 + d*16 + (c&15)
// k index = s;  kc = s>>3, e = s&7.  A-row m = i*32+c, B-row n = j*32+d.

// ---------------------------------------------------------------------------
__global__ __launch_bounds__(256) void prep_wout(const float* __restrict__ Wout,
                                                 __bf16* __restrict__ WT) {
  const int idx = blockIdx.x * 256 + threadIdx.x;  // 131072
  const int e = idx >> 10, kk = idx & 1023;
  const int round = kk >> 9, rem = kk & 511, d = rem >> 4, cp = rem & 15;
  const int c = round * 16 + cp;
  WT[idx] = (__bf16)Wout[(size_t)(c * 32 + d) * CZ + e];
}

// ---------------------------------------------------------------------------
__global__ __launch_bounds__(256) void prep_norm(const float* __restrict__ mask,
                                                 float* __restrict__ rnorm) {
  __shared__ float mi[512];
  const int i = blockIdx.x, t = threadIdx.x;
  mi[t]       = mask[(size_t)t * NT + i];
  mi[t + 256] = mask[(size_t)(t + 256) * NT + i];
  __syncthreads();
  for (int j = t; j < NT; j += 256) {
    float acc = 0.f;
#pragma unroll 4
    for (int s = 0; s < NS; ++s) acc += mi[s] * mask[(size_t)s * NT + j];
    rnorm[(size_t)i * NT + j] = 1.0f / (acc + 0.001f);
  }
}

// ---------------------------------------------------------------------------
// LN + projections, writing the tiled layouts. One wave per (i, 64-s chunk).
// LDS: bf16 transpose buffer T aliases the fp32 tile (single-wave block;
// explicit __syncthreads() fences the type-punned overwrite).
// ---------------------------------------------------------------------------
__global__ __launch_bounds__(64) void ln_proj(const float* __restrict__ feat,
                                              const float* __restrict__ mask,
                                              const float* __restrict__ gamma,
                                              const float* __restrict__ beta,
                                              const float* __restrict__ Wa,
                                              const float* __restrict__ Wb,
                                              __bf16* __restrict__ Abf,
                                              __bf16* __restrict__ Bbf) {
  __shared__ __align__(16) float ubuf[64 * 65];    // fp32 tile, row stride 65
  __bf16* T = (__bf16*)ubuf;                       // alias: 32*72 bf16 = 4608 B
  const int bid = blockIdx.x;    // 3072
  const int i = bid >> 3;
  const int s0 = (bid & 7) << 6;
  const int lane = threadIdx.x;
  const int l31 = lane & 31, lh = lane >> 5;

  const int rsub = lane >> 4, cb = (lane & 15) * 4;
#pragma unroll
  for (int rr = 0; rr < 16; ++rr) {
    const int row = rr * 4 + rsub;
    const float4 v = *(const float4*)(feat + ((size_t)(s0 + row) * NT + i) * 64 + cb);
    ubuf[row * 65 + cb] = v.x; ubuf[row * 65 + cb + 1] = v.y;
    ubuf[row * 65 + cb + 2] = v.z; ubuf[row * 65 + cb + 3] = v.w;
  }
  __syncthreads();

  float x[64];
#pragma unroll
  for (int k = 0; k < 64; ++k) x[k] = ubuf[lane * 65 + k];  // lane = s-row

  float mu = 0.f;
#pragma unroll
  for (int k = 0; k < 64; ++k) mu += x[k];
  mu *= (1.0f / 64.0f);
  float var = 0.f;
#pragma unroll
  for (int k = 0; k < 64; ++k) { const float d = x[k] - mu; var += d * d; }
  var *= (1.0f / 64.0f);
  const float rstd = rsqrtf(var + 1e-5f);
#pragma unroll
  for (int k = 0; k < 64; ++k)
    x[k] = (x[k] - mu) * rstd * gamma[k] + beta[k];

  const float mv = mask[(size_t)(s0 + lane) * NT + i];

  // ---- projection A ----
  float acc[32];
#pragma unroll
  for (int c = 0; c < 32; ++c) acc[c] = 0.f;
#pragma unroll 8
  for (int k = 0; k < 64; ++k) {
    const float mk = x[k];
#pragma unroll
    for (int c = 0; c < 32; ++c) acc[c] = fmaf(mk, Wa[k * 32 + c], acc[c]);
  }
  __syncthreads();  // fence: all fp32 tile reads complete before T overwrites it
#pragma unroll
  for (int c = 0; c < 32; ++c) T[c * 72 + lane] = (__bf16)(acc[c] * mv);
  __syncthreads();
  {
    // dest: rb=i>>2, r=(i&3)*32+c, kc = s0/8 + kc_loc, e = s&7
    __bf16* dst = Abf + (size_t)(i >> 2) * 65536 + (size_t)(s0 >> 3) * 1024 +
                  (size_t)((i & 3) * 32) * 8;
#pragma unroll
    for (int q = 0; q < 4; ++q) {
      const bf16x8 v = *(const bf16x8*)(T + l31 * 72 + (q * 2 + lh) * 8);
      *(bf16x8*)(dst + (size_t)(q * 2 + lh) * 1024 + l31 * 8) = v;
    }
  }
  __syncthreads();

  // ---- projection B ----
#pragma unroll
  for (int c = 0; c < 32; ++c) acc[c] = 0.f;
#pragma unroll 8
  for (int k = 0; k < 64; ++k) {
    const float mk = x[k];
#pragma unroll
    for (int c = 0; c < 32; ++c) acc[c] = fmaf(mk, Wb[k * 32 + c], acc[c]);
  }
#pragma unroll
  for (int c = 0; c < 32; ++c) T[c * 72 + lane] = (__bf16)(acc[c] * mv);
  __syncthreads();
  {
    __bf16* dst = Bbf + (size_t)(i >> 3) * 131072 + (size_t)(s0 >> 3) * 2048 +
                  (size_t)((i & 7) * 32) * 8;
#pragma unroll
    for (int q = 0; q < 4; ++q) {
      const bf16x8 v = *(const bf16x8*)(T + l31 * 72 + (q * 2 + lh) * 8);
      *(bf16x8*)(dst + (size_t)(q * 2 + lh) * 2048 + l31 * 8) = v;
    }
  }
}

// ---------------------------------------------------------------------------
// Fused GEMM, phase-interleaved 256x256 template (r3 lesson: occupancy is NOT
// the limit; the 2-phase stage/drain/barrier structure is — port the verified
// 8-phase-style schedule).
//   Block 256x256, 512 threads, 8 waves (wm 2 x wn 4), wave tile 128x64,
//   acc = 4x2 frags 32x32x16 = 128 AGPR -> 2 waves/SIMD (intended).
//   K = 512 = 8 K-tiles of BK=64. LDS 128 KB: 2 buffers x (A 8kc x 256r x 8e
//   + B same) = 2 x 32768 elems. 1 block/CU.
//   Per K-tile: 4 phases (one per k-slice ks). Phase j:
//     6 ds_read_b128 (quadrant j) | issue 2 global_load_lds (tile t+1, quad j)
//     s_waitcnt vmcnt(6)   <- guarantees NEXT phase's quadrant landed;
//                             6 loads stay in flight across the barrier
//     s_barrier; lgkmcnt(0); sched_barrier; setprio(1); 8 MFMA; setprio(0)
//   Tail tile peeled with waits 4/2/0. No vmcnt(0) in steady state.
//   Grid 48x48 bm-major: XCD = bm mod 8 -> per-XCD A set 1.5 MB, L2-resident.
// Epilogue: 64 (i,j) pairs; P[p][d][c'] stride 648/20 (r0's proven
// zero-conflict addressing); GEMM2 16x16x32, waves split 2p x 4e (WT read
// duplication 2x, half of r0); z accumulates across the two c-half rounds.
// ---------------------------------------------------------------------------
#define VMCNT(N) asm volatile("s_waitcnt vmcnt(" #N ")" ::: "memory")

__global__ __launch_bounds__(512, 2) void opm_gemm(const __bf16* __restrict__ A,
                                                   const __bf16* __restrict__ B,
                                                   const __bf16* __restrict__ WT,
                                                   const float* __restrict__ bout,
                                                   const float* __restrict__ rnorm,
                                                   float* __restrict__ out) {
  __shared__ __align__(16) __bf16 smem[65536];  // 131072 B
  // buffer b (b=0/1): As = smem + b*32768 ([kc 8][r 256][e 8]), Bs = As+16384
  // epilogue alias: P[p][d][c'] at p*648 + d*20 + c', p<64 (41472 elems)

  const int tid = threadIdx.x, lane = tid & 63, wid = tid >> 6;
  const int wm = wid & 1, wn = wid >> 1;         // 2 x 4 wave grid
  const int l31 = lane & 31, lh = lane >> 5;
  const int l15 = lane & 15, lq = lane >> 4;     // epilogue 16x16 indexing
  const int bm = blockIdx.x % 48, bn = blockIdx.x / 48;

  // Staging decomposition: thread tid loads LDS elems [q*4096 + tid*8 .. +8)
  // of each quadrant q (A and B regions). kc_loc = tid>>8, r = tid&255.
  const int r8 = tid & 255, kcl = tid >> 8;
  const size_t aBase = (size_t)(bm * 2 + (r8 >> 7)) * 65536 + (size_t)kcl * 1024 +
                       (size_t)(r8 & 127) * 8;
  const size_t bBase = (size_t)bn * 131072 + (size_t)kcl * 2048 + (size_t)r8 * 8;
  const int wb512 = wid * 512;  // wave-uniform LDS base (lane*16B added by HW)

  floatx16 acc[4][2];
#pragma unroll
  for (int fm = 0; fm < 4; ++fm)
#pragma unroll
    for (int fn = 0; fn < 2; ++fn)
#pragma unroll
      for (int q = 0; q < 16; ++q) acc[fm][fn][q] = 0.f;

#define STAGE2(j)                                                               \
  {                                                                             \
    __builtin_amdgcn_global_load_lds(                                           \
        (const __attribute__((address_space(1))) void*)(A + aO +                \
            (size_t)(2 * (j)) * 1024),                                          \
        (__attribute__((address_space(3))) void*)(smem + dstOff + (j) * 4096 +  \
                                                  wb512), 16, 0, 0);            \
    __builtin_amdgcn_global_load_lds(                                           \
        (const __attribute__((address_space(1))) void*)(B + bO +                \
            (size_t)(2 * (j)) * 2048),                                          \
        (__attribute__((address_space(3))) void*)(smem + dstOff + 16384 +       \
                                                  (j) * 4096 + wb512), 16, 0, 0); \
  }

#define PHASE(j, As, Bs, STMT, WAIT)                                            \
  {                                                                             \
    const int ck = (j) * 2 + lh;                                                \
    const bf16x8 af0 = *(const bf16x8*)((As) + ck * 2048 + (wm * 128 + l31) * 8);      \
    const bf16x8 af1 = *(const bf16x8*)((As) + ck * 2048 + (wm * 128 + 32 + l31) * 8); \
    const bf16x8 af2 = *(const bf16x8*)((As) + ck * 2048 + (wm * 128 + 64 + l31) * 8); \
    const bf16x8 af3 = *(const bf16x8*)((As) + ck * 2048 + (wm * 128 + 96 + l31) * 8); \
    const bf16x8 bf0 = *(const bf16x8*)((Bs) + ck * 2048 + (wn * 64 + l31) * 8);       \
    const bf16x8 bf1 = *(const bf16x8*)((Bs) + ck * 2048 + (wn * 64 + 32 + l31) * 8);  \
    STMT;                                                                       \
    WAIT;                                                                       \
    __builtin_amdgcn_s_barrier();                                               \
    asm volatile("s_waitcnt lgkmcnt(0)" ::: "memory");                          \
    __builtin_amdgcn_sched_barrier(0);                                          \
    __builtin_amdgcn_s_setprio(1);                                              \
    acc[0][0] = __builtin_amdgcn_mfma_f32_32x32x16_bf16(af0, bf0, acc[0][0], 0, 0, 0); \
    acc[0][1] = __builtin_amdgcn_mfma_f32_32x32x16_bf16(af0, bf1, acc[0][1], 0, 0, 0); \
    acc[1][0] = __builtin_amdgcn_mfma_f32_32x32x16_bf16(af1, bf0, acc[1][0], 0, 0, 0); \
    acc[1][1] = __builtin_amdgcn_mfma_f32_32x32x16_bf16(af1, bf1, acc[1][1], 0, 0, 0); \
    acc[2][0] = __builtin_amdgcn_mfma_f32_32x32x16_bf16(af2, bf0, acc[2][0], 0, 0, 0); \
    acc[2][1] = __builtin_amdgcn_mfma_f32_32x32x16_bf16(af2, bf1, acc[2][1], 0, 0, 0); \
    acc[3][0] = __builtin_amdgcn_mfma_f32_32x32x16_bf16(af3, bf0, acc[3][0], 0, 0, 0); \
    acc[3][1] = __builtin_amdgcn_mfma_f32_32x32x16_bf16(af3, bf1, acc[3][1], 0, 0, 0); \
    __builtin_amdgcn_s_setprio(0);                                              \
  }

  // Prologue: stage tile 0 fully into buf0, drain, publish.
  {
    const size_t aO = aBase;
    const size_t bO = bBase;
    const int dstOff = 0;
#pragma unroll
    for (int j = 0; j < 4; ++j) STAGE2(j);
  }
  VMCNT(0);
  __builtin_amdgcn_s_barrier();

  // Steady state: tiles 0..6, staging tile t+1 spread across the 4 phases.
  for (int t = 0; t < 7; ++t) {
    const __bf16* As = smem + ((t & 1) ? 32768 : 0);
    const __bf16* Bs = As + 16384;
    const int dstOff = (t & 1) ? 0 : 32768;
    const size_t aO = aBase + (size_t)(t + 1) * 8192;
    const size_t bO = bBase + (size_t)(t + 1) * 16384;
    PHASE(0, As, Bs, STAGE2(0), VMCNT(6));
    PHASE(1, As, Bs, STAGE2(1), VMCNT(6));
    PHASE(2, As, Bs, STAGE2(2), VMCNT(6));
    PHASE(3, As, Bs, STAGE2(3), VMCNT(6));
  }
  // Tail: tile 7 (staged during t=6), drain 4 -> 2 -> 0.
  {
    const __bf16* As = smem + 32768;
    const __bf16* Bs = As + 16384;
    PHASE(0, As, Bs, (void)0, VMCNT(4));
    PHASE(1, As, Bs, (void)0, VMCNT(2));
    PHASE(2, As, Bs, (void)0, VMCNT(0));
    PHASE(3, As, Bs, (void)0, (void)0);
  }
#undef PHASE
#undef STAGE2

  // ---- epilogue: 2 rounds over c-halves, z accumulates over rounds ----
  floatx4 zf[2][2];
#pragma unroll
  for (int ps = 0; ps < 2; ++ps)
#pragma unroll
    for (int ef = 0; ef < 2; ++ef)
#pragma unroll
      for (int q = 0; q < 4; ++q) zf[ps][ef][q] = 0.f;
  const int pg = wid & 1, eg = wid >> 1;  // 2 p-groups x 4 e-groups

#pragma unroll
  for (int round = 0; round < 2; ++round) {
    __syncthreads();  // main-loop reads / previous GEMM2 reads complete
    // scatter: p = (wm*4+fm)*8 + wn*2+fn; P[p][d=l31][c'], d-stride 20,
    // c' = 8*qp + 4*lh + j  (c = 16*round + c', acc reg = round*8+qp*4+j)
#pragma unroll
    for (int fm = 0; fm < 4; ++fm)
#pragma unroll
      for (int fn = 0; fn < 2; ++fn) {
        const int p = (wm * 4 + fm) * 8 + wn * 2 + fn;
        __bf16* base = smem + p * 648 + l31 * 20 + lh * 4;
#pragma unroll
        for (int qp = 0; qp < 2; ++qp) {
          bf16x4 v;
#pragma unroll
          for (int j = 0; j < 4; ++j)
            v[j] = (__bf16)acc[fm][fn][round * 8 + qp * 4 + j];
          *(bf16x4*)(base + qp * 8) = v;
        }
      }
    __syncthreads();
    // GEMM2 (16x16x32): z[p][e] += P[p][k] * WT[e][round*512+k], K=512.
    // Wave (pg,eg): p in [pg*32,+32) (2 frags), e in [eg*32,+32) (2 frags).
    // k = ks*32 + lq*8: P addr = row*648 + ks*40 + (lq>>1)*20 + (lq&1)*8.
    const int pAddr = lq ? (((lq >> 1) * 20) + ((lq & 1) * 8)) : 0;
    const __bf16* p0 = smem + (pg * 32 + l15) * 648 + pAddr;
    const __bf16* p1 = p0 + 16 * 648;
    const __bf16* w0 = WT + (size_t)(eg * 32 + l15) * 1024 + round * 512 + lq * 8;
    const __bf16* w1 = w0 + (size_t)16 * 1024;
#pragma unroll 4
    for (int ks = 0; ks < 16; ++ks) {
      const bf16x8 pa0 = *(const bf16x8*)(p0 + ks * 40);
      const bf16x8 pa1 = *(const bf16x8*)(p1 + ks * 40);
      const bf16x8 wb0 = *(const bf16x8*)(w0 + ks * 32);
      const bf16x8 wb1 = *(const bf16x8*)(w1 + ks * 32);
      zf[0][0] = __builtin_amdgcn_mfma_f32_16x16x32_bf16(pa0, wb0, zf[0][0], 0, 0, 0);
      zf[0][1] = __builtin_amdgcn_mfma_f32_16x16x32_bf16(pa0, wb1, zf[0][1], 0, 0, 0);
      zf[1][0] = __builtin_amdgcn_mfma_f32_16x16x32_bf16(pa1, wb0, zf[1][0], 0, 0, 0);
      zf[1][1] = __builtin_amdgcn_mfma_f32_16x16x32_bf16(pa1, wb1, zf[1][1], 0, 0, 0);
    }
  }

  // out[i][j][e] = (z + bout[e]) * rnorm[i][j]; D-frag: row p = lq*4+q,
  // col e = l15 (within each 16-frag).
#pragma unroll
  for (int ps = 0; ps < 2; ++ps)
#pragma unroll
    for (int ef = 0; ef < 2; ++ef) {
      const int e = eg * 32 + ef * 16 + l15;
      const float be = bout[e];
#pragma unroll
      for (int q = 0; q < 4; ++q) {
        const int p = pg * 32 + ps * 16 + lq * 4 + q;
        const int i = bm * 8 + (p >> 3), j = bn * 8 + (p & 7);
        const float rn = rnorm[(size_t)i * NT + j];
        out[((size_t)i * NT + j) * CZ + e] = (zf[ps][ef][q] + be) * rn;
      }
    }
}

// ---------------------------------------------------------------------------
extern "C" void kernel_launch(void* const* d_in, const int* in_sizes, int n_in,
                              void* d_out, int out_size, void* d_ws, size_t ws_size,
                              hipStream_t stream) {
  const float* feat  = (const float*)d_in[0];
  const float* mask  = (const float*)d_in[1];
  const float* gamma = (const float*)d_in[2];
  const float* beta  = (const float*)d_in[3];
  const float* Wa    = (const float*)d_in[4];
  const float* Wb    = (const float*)d_in[5];
  const float* Wout  = (const float*)d_in[6];
  const float* bout  = (const float*)d_in[7];
  float* out = (float*)d_out;

  char* ws = (char*)d_ws;
  const size_t AB_BYTES = (size_t)96 * 65536 * sizeof(__bf16);  // 12,582,912
  __bf16* Abf = (__bf16*)(ws);
  __bf16* Bbf = (__bf16*)(ws + AB_BYTES);
  __bf16* WT  = (__bf16*)(ws + 2 * AB_BYTES);
  float* rnorm = (float*)(ws + 2 * AB_BYTES + (size_t)CZ * 1024 * sizeof(__bf16));

  prep_wout<<<512, 256, 0, stream>>>(Wout, WT);
  prep_norm<<<NT, 256, 0, stream>>>(mask, rnorm);
  ln_proj<<<NT * (NS / 64), 64, 0, stream>>>(feat, mask, gamma, beta, Wa, Wb, Abf, Bbf);
  opm_gemm<<<48 * 48, 512, 0, stream>>>(Abf, Bbf, WT, bout, rnorm, out);
}

// Round 5
// 483.370 us; speedup vs baseline: 1.1363x; 1.0033x over previous
//
#include <hip/hip_runtime.h>
#include <cstdint>
#include <cstddef>

#define NS 512
#define NT 384
#define CZ 128

typedef __bf16 bf16x8 __attribute__((ext_vector_type(8)));
typedef __bf16 bf16x4 __attribute__((ext_vector_type(4)));
typedef float floatx16 __attribute__((ext_vector_type(16)));
typedef float floatx4 __attribute__((ext_vector_type(4)));

// Workspace layouts (bf16 element units):
//   A_t[rb(96)][kc(64)][r(128)][e(8)]   panel = 65536 elems (128 rows, k=s)
//   B_t[pb(48)][kc(64)][r(256)][e(8)]   panel = 131072 elems
//   WT [e(128)][k(1024)]  k = (c>>4)*512 + d*16 + (c&15)
// k index = s;  kc = s>>3, e = s&7.  A-row m = i*32+c, B-row n = j*32+d.

// ---------------------------------------------------------------------------
__global__ __launch_bounds__(256) void prep_wout(const float* __restrict__ Wout,
                                                 __bf16* __restrict__ WT) {
  const int idx = blockIdx.x * 256 + threadIdx.x;  // 131072
  const int e = idx >> 10, kk = idx & 1023;
  const int round = kk >> 9, rem = kk & 511, d = rem >> 4, cp = rem & 15;
  const int c = round * 16 + cp;
  WT[idx] = (__bf16)Wout[(size_t)(c * 32 + d) * CZ + e];
}

// ---------------------------------------------------------------------------
__global__ __launch_bounds__(256) void prep_norm(const float* __restrict__ mask,
                                                 float* __restrict__ rnorm) {
  __shared__ float mi[512];
  const int i = blockIdx.x, t = threadIdx.x;
  mi[t]       = mask[(size_t)t * NT + i];
  mi[t + 256] = mask[(size_t)(t + 256) * NT + i];
  __syncthreads();
  for (int j = t; j < NT; j += 256) {
    float acc = 0.f;
#pragma unroll 4
    for (int s = 0; s < NS; ++s) acc += mi[s] * mask[(size_t)s * NT + j];
    rnorm[(size_t)i * NT + j] = 1.0f / (acc + 0.001f);
  }
}

// ---------------------------------------------------------------------------
// LN + projections, writing the tiled layouts. One wave per (i, 64-s chunk).
// LDS: bf16 transpose buffer T aliases the fp32 tile (single-wave block;
// explicit __syncthreads() fences the type-punned overwrite).
// ---------------------------------------------------------------------------
__global__ __launch_bounds__(64) void ln_proj(const float* __restrict__ feat,
                                              const float* __restrict__ mask,
                                              const float* __restrict__ gamma,
                                              const float* __restrict__ beta,
                                              const float* __restrict__ Wa,
                                              const float* __restrict__ Wb,
                                              __bf16* __restrict__ Abf,
                                              __bf16* __restrict__ Bbf) {
  __shared__ __align__(16) float ubuf[64 * 65];    // fp32 tile, row stride 65
  __bf16* T = (__bf16*)ubuf;                       // alias: 32*72 bf16 = 4608 B
  const int bid = blockIdx.x;    // 3072
  const int i = bid >> 3;
  const int s0 = (bid & 7) << 6;
  const int lane = threadIdx.x;
  const int l31 = lane & 31, lh = lane >> 5;

  const int rsub = lane >> 4, cb = (lane & 15) * 4;
#pragma unroll
  for (int rr = 0; rr < 16; ++rr) {
    const int row = rr * 4 + rsub;
    const float4 v = *(const float4*)(feat + ((size_t)(s0 + row) * NT + i) * 64 + cb);
    ubuf[row * 65 + cb] = v.x; ubuf[row * 65 + cb + 1] = v.y;
    ubuf[row * 65 + cb + 2] = v.z; ubuf[row * 65 + cb + 3] = v.w;
  }
  __syncthreads();

  float x[64];
#pragma unroll
  for (int k = 0; k < 64; ++k) x[k] = ubuf[lane * 65 + k];  // lane = s-row

  float mu = 0.f;
#pragma unroll
  for (int k = 0; k < 64; ++k) mu += x[k];
  mu *= (1.0f / 64.0f);
  float var = 0.f;
#pragma unroll
  for (int k = 0; k < 64; ++k) { const float d = x[k] - mu; var += d * d; }
  var *= (1.0f / 64.0f);
  const float rstd = rsqrtf(var + 1e-5f);
#pragma unroll
  for (int k = 0; k < 64; ++k)
    x[k] = (x[k] - mu) * rstd * gamma[k] + beta[k];

  const float mv = mask[(size_t)(s0 + lane) * NT + i];

  // ---- projection A ----
  float acc[32];
#pragma unroll
  for (int c = 0; c < 32; ++c) acc[c] = 0.f;
#pragma unroll 8
  for (int k = 0; k < 64; ++k) {
    const float mk = x[k];
#pragma unroll
    for (int c = 0; c < 32; ++c) acc[c] = fmaf(mk, Wa[k * 32 + c], acc[c]);
  }
  __syncthreads();  // fence: all fp32 tile reads complete before T overwrites it
#pragma unroll
  for (int c = 0; c < 32; ++c) T[c * 72 + lane] = (__bf16)(acc[c] * mv);
  __syncthreads();
  {
    // dest: rb=i>>2, r=(i&3)*32+c, kc = s0/8 + kc_loc, e = s&7
    __bf16* dst = Abf + (size_t)(i >> 2) * 65536 + (size_t)(s0 >> 3) * 1024 +
                  (size_t)((i & 3) * 32) * 8;
#pragma unroll
    for (int q = 0; q < 4; ++q) {
      const bf16x8 v = *(const bf16x8*)(T + l31 * 72 + (q * 2 + lh) * 8);
      *(bf16x8*)(dst + (size_t)(q * 2 + lh) * 1024 + l31 * 8) = v;
    }
  }
  __syncthreads();

  // ---- projection B ----
#pragma unroll
  for (int c = 0; c < 32; ++c) acc[c] = 0.f;
#pragma unroll 8
  for (int k = 0; k < 64; ++k) {
    const float mk = x[k];
#pragma unroll
    for (int c = 0; c < 32; ++c) acc[c] = fmaf(mk, Wb[k * 32 + c], acc[c]);
  }
#pragma unroll
  for (int c = 0; c < 32; ++c) T[c * 72 + lane] = (__bf16)(acc[c] * mv);
  __syncthreads();
  {
    __bf16* dst = Bbf + (size_t)(i >> 3) * 131072 + (size_t)(s0 >> 3) * 2048 +
                  (size_t)((i & 7) * 32) * 8;
#pragma unroll
    for (int q = 0; q < 4; ++q) {
      const bf16x8 v = *(const bf16x8*)(T + l31 * 72 + (q * 2 + lh) * 8);
      *(bf16x8*)(dst + (size_t)(q * 2 + lh) * 2048 + l31 * 8) = v;
    }
  }
}

// ---------------------------------------------------------------------------
// Fused GEMM, phase-interleaved 256x256 template.
// ROUND-5 CHANGE (single variable): 2D XCD-co-resident block mapping.
//   xcd = bid & 7 (HW round-robin), idx = bid >> 3 (0..287),
//   bm = xcd*6 + idx%6, bn = idx/6.
//   => each XCD exclusively owns a 6-row A band (1.5 MB, L2-resident for the
//   whole kernel) and walks bn with a ~6-panel sliding B window (1.5 MB).
//   Footprint/XCD ~3.25 MB < 4 MB L2. Old mapping (bm mod 8) streamed all of
//   B (12.6 MB) through every XCD's L2 -> ~590 MB chip-wide L3 traffic at
//   ~600 cy latency = the 70% stall (r4 lesson: MFMA cycle model says
//   32 cy/SIMD per 32x32x16; issue-work explains only ~30% of runtime).
// Structure unchanged from r4: 512 thr, 8 waves (2m x 4n), wave 128x64,
// BK=64, 4 phases/K-tile, vmcnt(6) steady (tail 4/2/0), raw barriers,
// setprio around MFMA. Epilogue unchanged.
// ---------------------------------------------------------------------------
#define VMCNT(N) asm volatile("s_waitcnt vmcnt(" #N ")" ::: "memory")

__global__ __launch_bounds__(512, 2) void opm_gemm(const __bf16* __restrict__ A,
                                                   const __bf16* __restrict__ B,
                                                   const __bf16* __restrict__ WT,
                                                   const float* __restrict__ bout,
                                                   const float* __restrict__ rnorm,
                                                   float* __restrict__ out) {
  __shared__ __align__(16) __bf16 smem[65536];  // 131072 B
  // buffer b (b=0/1): As = smem + b*32768 ([kc 8][r 256][e 8]), Bs = As+16384
  // epilogue alias: P[p][d][c'] at p*648 + d*20 + c', p<64 (41472 elems)

  const int tid = threadIdx.x, lane = tid & 63, wid = tid >> 6;
  const int wm = wid & 1, wn = wid >> 1;         // 2 x 4 wave grid
  const int l31 = lane & 31, lh = lane >> 5;
  const int l15 = lane & 15, lq = lane >> 4;     // epilogue 16x16 indexing
  const int xcd = blockIdx.x & 7, idx = blockIdx.x >> 3;  // idx in [0,288)
  const int bm = xcd * 6 + idx % 6, bn = idx / 6;

  // Staging decomposition: thread tid loads LDS elems [q*4096 + tid*8 .. +8)
  // of each quadrant q (A and B regions). kc_loc = tid>>8, r = tid&255.
  const int r8 = tid & 255, kcl = tid >> 8;
  const size_t aBase = (size_t)(bm * 2 + (r8 >> 7)) * 65536 + (size_t)kcl * 1024 +
                       (size_t)(r8 & 127) * 8;
  const size_t bBase = (size_t)bn * 131072 + (size_t)kcl * 2048 + (size_t)r8 * 8;
  const int wb512 = wid * 512;  // wave-uniform LDS base (lane*16B added by HW)

  floatx16 acc[4][2];
#pragma unroll
  for (int fm = 0; fm < 4; ++fm)
#pragma unroll
    for (int fn = 0; fn < 2; ++fn)
#pragma unroll
      for (int q = 0; q < 16; ++q) acc[fm][fn][q] = 0.f;

#define STAGE2(j)                                                               \
  {                                                                             \
    __builtin_amdgcn_global_load_lds(                                           \
        (const __attribute__((address_space(1))) void*)(A + aO +                \
            (size_t)(2 * (j)) * 1024),                                          \
        (__attribute__((address_space(3))) void*)(smem + dstOff + (j) * 4096 +  \
                                                  wb512), 16, 0, 0);            \
    __builtin_amdgcn_global_load_lds(                                           \
        (const __attribute__((address_space(1))) void*)(B + bO +                \
            (size_t)(2 * (j)) * 2048),                                          \
        (__attribute__((address_space(3))) void*)(smem + dstOff + 16384 +       \
                                                  (j) * 4096 + wb512), 16, 0, 0); \
  }

#define PHASE(j, As, Bs, STMT, WAIT)                                            \
  {                                                                             \
    const int ck = (j) * 2 + lh;                                                \
    const bf16x8 af0 = *(const bf16x8*)((As) + ck * 2048 + (wm * 128 + l31) * 8);      \
    const bf16x8 af1 = *(const bf16x8*)((As) + ck * 2048 + (wm * 128 + 32 + l31) * 8); \
    const bf16x8 af2 = *(const bf16x8*)((As) + ck * 2048 + (wm * 128 + 64 + l31) * 8); \
    const bf16x8 af3 = *(const bf16x8*)((As) + ck * 2048 + (wm * 128 + 96 + l31) * 8); \
    const bf16x8 bf0 = *(const bf16x8*)((Bs) + ck * 2048 + (wn * 64 + l31) * 8);       \
    const bf16x8 bf1 = *(const bf16x8*)((Bs) + ck * 2048 + (wn * 64 + 32 + l31) * 8);  \
    STMT;                                                                       \
    WAIT;                                                                       \
    __builtin_amdgcn_s_barrier();                                               \
    asm volatile("s_waitcnt lgkmcnt(0)" ::: "memory");                          \
    __builtin_amdgcn_sched_barrier(0);                                          \
    __builtin_amdgcn_s_setprio(1);                                              \
    acc[0][0] = __builtin_amdgcn_mfma_f32_32x32x16_bf16(af0, bf0, acc[0][0], 0, 0, 0); \
    acc[0][1] = __builtin_amdgcn_mfma_f32_32x32x16_bf16(af0, bf1, acc[0][1], 0, 0, 0); \
    acc[1][0] = __builtin_amdgcn_mfma_f32_32x32x16_bf16(af1, bf0, acc[1][0], 0, 0, 0); \
    acc[1][1] = __builtin_amdgcn_mfma_f32_32x32x16_bf16(af1, bf1, acc[1][1], 0, 0, 0); \
    acc[2][0] = __builtin_amdgcn_mfma_f32_32x32x16_bf16(af2, bf0, acc[2][0], 0, 0, 0); \
    acc[2][1] = __builtin_amdgcn_mfma_f32_32x32x16_bf16(af2, bf1, acc[2][1], 0, 0, 0); \
    acc[3][0] = __builtin_amdgcn_mfma_f32_32x32x16_bf16(af3, bf0, acc[3][0], 0, 0, 0); \
    acc[3][1] = __builtin_amdgcn_mfma_f32_32x32x16_bf16(af3, bf1, acc[3][1], 0, 0, 0); \
    __builtin_amdgcn_s_setprio(0);                                              \
  }

  // Prologue: stage tile 0 fully into buf0, drain, publish.
  {
    const size_t aO = aBase;
    const size_t bO = bBase;
    const int dstOff = 0;
#pragma unroll
    for (int j = 0; j < 4; ++j) STAGE2(j);
  }
  VMCNT(0);
  __builtin_amdgcn_s_barrier();

  // Steady state: tiles 0..6, staging tile t+1 spread across the 4 phases.
  for (int t = 0; t < 7; ++t) {
    const __bf16* As = smem + ((t & 1) ? 32768 : 0);
    const __bf16* Bs = As + 16384;
    const int dstOff = (t & 1) ? 0 : 32768;
    const size_t aO = aBase + (size_t)(t + 1) * 8192;
    const size_t bO = bBase + (size_t)(t + 1) * 16384;
    PHASE(0, As, Bs, STAGE2(0), VMCNT(6));
    PHASE(1, As, Bs, STAGE2(1), VMCNT(6));
    PHASE(2, As, Bs, STAGE2(2), VMCNT(6));
    PHASE(3, As, Bs, STAGE2(3), VMCNT(6));
  }
  // Tail: tile 7 (staged during t=6), drain 4 -> 2 -> 0.
  {
    const __bf16* As = smem + 32768;
    const __bf16* Bs = As + 16384;
    PHASE(0, As, Bs, (void)0, VMCNT(4));
    PHASE(1, As, Bs, (void)0, VMCNT(2));
    PHASE(2, As, Bs, (void)0, VMCNT(0));
    PHASE(3, As, Bs, (void)0, (void)0);
  }
#undef PHASE
#undef STAGE2

  // ---- epilogue: 2 rounds over c-halves, z accumulates over rounds ----
  floatx4 zf[2][2];
#pragma unroll
  for (int ps = 0; ps < 2; ++ps)
#pragma unroll
    for (int ef = 0; ef < 2; ++ef)
#pragma unroll
      for (int q = 0; q < 4; ++q) zf[ps][ef][q] = 0.f;
  const int pg = wid & 1, eg = wid >> 1;  // 2 p-groups x 4 e-groups

#pragma unroll
  for (int round = 0; round < 2; ++round) {
    __syncthreads();  // main-loop reads / previous GEMM2 reads complete
    // scatter: p = (wm*4+fm)*8 + wn*2+fn; P[p][d=l31][c'], d-stride 20,
    // c' = 8*qp + 4*lh + j  (c = 16*round + c', acc reg = round*8+qp*4+j)
#pragma unroll
    for (int fm = 0; fm < 4; ++fm)
#pragma unroll
      for (int fn = 0; fn < 2; ++fn) {
        const int p = (wm * 4 + fm) * 8 + wn * 2 + fn;
        __bf16* base = smem + p * 648 + l31 * 20 + lh * 4;
#pragma unroll
        for (int qp = 0; qp < 2; ++qp) {
          bf16x4 v;
#pragma unroll
          for (int j = 0; j < 4; ++j)
            v[j] = (__bf16)acc[fm][fn][round * 8 + qp * 4 + j];
          *(bf16x4*)(base + qp * 8) = v;
        }
      }
    __syncthreads();
    // GEMM2 (16x16x32): z[p][e] += P[p][k] * WT[e][round*512+k], K=512.
    // Wave (pg,eg): p in [pg*32,+32) (2 frags), e in [eg*32,+32) (2 frags).
    // k = ks*32 + lq*8: P addr = row*648 + ks*40 + (lq>>1)*20 + (lq&1)*8.
    const int pAddr = lq ? (((lq >> 1) * 20) + ((lq & 1) * 8)) : 0;
    const __bf16* p0 = smem + (pg * 32 + l15) * 648 + pAddr;
    const __bf16* p1 = p0 + 16 * 648;
    const __bf16* w0 = WT + (size_t)(eg * 32 + l15) * 1024 + round * 512 + lq * 8;
    const __bf16* w1 = w0 + (size_t)16 * 1024;
#pragma unroll 4
    for (int ks = 0; ks < 16; ++ks) {
      const bf16x8 pa0 = *(const bf16x8*)(p0 + ks * 40);
      const bf16x8 pa1 = *(const bf16x8*)(p1 + ks * 40);
      const bf16x8 wb0 = *(const bf16x8*)(w0 + ks * 32);
      const bf16x8 wb1 = *(const bf16x8*)(w1 + ks * 32);
      zf[0][0] = __builtin_amdgcn_mfma_f32_16x16x32_bf16(pa0, wb0, zf[0][0], 0, 0, 0);
      zf[0][1] = __builtin_amdgcn_mfma_f32_16x16x32_bf16(pa0, wb1, zf[0][1], 0, 0, 0);
      zf[1][0] = __builtin_amdgcn_mfma_f32_16x16x32_bf16(pa1, wb0, zf[1][0], 0, 0, 0);
      zf[1][1] = __builtin_amdgcn_mfma_f32_16x16x32_bf16(pa1, wb1, zf[1][1], 0, 0, 0);
    }
  }

  // out[i][j][e] = (z + bout[e]) * rnorm[i][j]; D-frag: row p = lq*4+q,
  // col e = l15 (within each 16-frag).
#pragma unroll
  for (int ps = 0; ps < 2; ++ps)
#pragma unroll
    for (int ef = 0; ef < 2; ++ef) {
      const int e = eg * 32 + ef * 16 + l15;
      const float be = bout[e];
#pragma unroll
      for (int q = 0; q < 4; ++q) {
        const int p = pg * 32 + ps * 16 + lq * 4 + q;
        const int i = bm * 8 + (p >> 3), j = bn * 8 + (p & 7);
        const float rn = rnorm[(size_t)i * NT + j];
        out[((size_t)i * NT + j) * CZ + e] = (zf[ps][ef][q] + be) * rn;
      }
    }
}

// ---------------------------------------------------------------------------
extern "C" void kernel_launch(void* const* d_in, const int* in_sizes, int n_in,
                              void* d_out, int out_size, void* d_ws, size_t ws_size,
                              hipStream_t stream) {
  const float* feat  = (const float*)d_in[0];
  const float* mask  = (const float*)d_in[1];
  const float* gamma = (const float*)d_in[2];
  const float* beta  = (const float*)d_in[3];
  const float* Wa    = (const float*)d_in[4];
  const float* Wb    = (const float*)d_in[5];
  const float* Wout  = (const float*)d_in[6];
  const float* bout  = (const float*)d_in[7];
  float* out = (float*)d_out;

  char* ws = (char*)d_ws;
  const size_t AB_BYTES = (size_t)96 * 65536 * sizeof(__bf16);  // 12,582,912
  __bf16* Abf = (__bf16*)(ws);
  __bf16* Bbf = (__bf16*)(ws + AB_BYTES);
  __bf16* WT  = (__bf16*)(ws + 2 * AB_BYTES);
  float* rnorm = (float*)(ws + 2 * AB_BYTES + (size_t)CZ * 1024 * sizeof(__bf16));

  prep_wout<<<512, 256, 0, stream>>>(Wout, WT);
  prep_norm<<<NT, 256, 0, stream>>>(mask, rnorm);
  ln_proj<<<NT * (NS / 64), 64, 0, stream>>>(feat, mask, gamma, beta, Wa, Wb, Abf, Bbf);
  opm_gemm<<<48 * 48, 512, 0, stream>>>(Abf, Bbf, WT, bout, rnorm, out);
}

// Round 6
// 428.443 us; speedup vs baseline: 1.2820x; 1.1282x over previous
//
#include <hip/hip_runtime.h>
#include <cstdint>
#include <cstddef>

#define NS 512
#define NT 384
#define CZ 128

typedef __bf16 bf16x8 __attribute__((ext_vector_type(8)));
typedef __bf16 bf16x4 __attribute__((ext_vector_type(4)));
typedef float floatx16 __attribute__((ext_vector_type(16)));
typedef float floatx4 __attribute__((ext_vector_type(4)));

// Workspace layouts (bf16 element units):
//   A_t[rb(96)][kc(64)][r(128)][e(8)]   panel = 65536 elems (128 rows, k=s)
//   B_t[pb(48)][kc(64)][r(256)][e(8)]   panel = 131072 elems
//   WT [e(128)][k(1024)]  k = (c>>4)*512 + d*16 + (c&15)
// k index = s;  kc = s>>3, e = s&7.  A-row m = i*32+c, B-row n = j*32+d.

// ---------------------------------------------------------------------------
__global__ __launch_bounds__(256) void prep_wout(const float* __restrict__ Wout,
                                                 __bf16* __restrict__ WT) {
  const int idx = blockIdx.x * 256 + threadIdx.x;  // 131072
  const int e = idx >> 10, kk = idx & 1023;
  const int round = kk >> 9, rem = kk & 511, d = rem >> 4, cp = rem & 15;
  const int c = round * 16 + cp;
  WT[idx] = (__bf16)Wout[(size_t)(c * 32 + d) * CZ + e];
}

// ---------------------------------------------------------------------------
__global__ __launch_bounds__(256) void prep_norm(const float* __restrict__ mask,
                                                 float* __restrict__ rnorm) {
  __shared__ float mi[512];
  const int i = blockIdx.x, t = threadIdx.x;
  mi[t]       = mask[(size_t)t * NT + i];
  mi[t + 256] = mask[(size_t)(t + 256) * NT + i];
  __syncthreads();
  for (int j = t; j < NT; j += 256) {
    float acc = 0.f;
#pragma unroll 4
    for (int s = 0; s < NS; ++s) acc += mi[s] * mask[(size_t)s * NT + j];
    rnorm[(size_t)i * NT + j] = 1.0f / (acc + 0.001f);
  }
}

// ---------------------------------------------------------------------------
// LN + projections, writing the tiled layouts. One wave per (i, 64-s chunk).
// LDS: bf16 transpose buffer T aliases the fp32 tile (single-wave block;
// explicit __syncthreads() fences the type-punned overwrite).
// ---------------------------------------------------------------------------
__global__ __launch_bounds__(64) void ln_proj(const float* __restrict__ feat,
                                              const float* __restrict__ mask,
                                              const float* __restrict__ gamma,
                                              const float* __restrict__ beta,
                                              const float* __restrict__ Wa,
                                              const float* __restrict__ Wb,
                                              __bf16* __restrict__ Abf,
                                              __bf16* __restrict__ Bbf) {
  __shared__ __align__(16) float ubuf[64 * 65];    // fp32 tile, row stride 65
  __bf16* T = (__bf16*)ubuf;                       // alias: 32*72 bf16 = 4608 B
  const int bid = blockIdx.x;    // 3072
  const int i = bid >> 3;
  const int s0 = (bid & 7) << 6;
  const int lane = threadIdx.x;
  const int l31 = lane & 31, lh = lane >> 5;

  const int rsub = lane >> 4, cb = (lane & 15) * 4;
#pragma unroll
  for (int rr = 0; rr < 16; ++rr) {
    const int row = rr * 4 + rsub;
    const float4 v = *(const float4*)(feat + ((size_t)(s0 + row) * NT + i) * 64 + cb);
    ubuf[row * 65 + cb] = v.x; ubuf[row * 65 + cb + 1] = v.y;
    ubuf[row * 65 + cb + 2] = v.z; ubuf[row * 65 + cb + 3] = v.w;
  }
  __syncthreads();

  float x[64];
#pragma unroll
  for (int k = 0; k < 64; ++k) x[k] = ubuf[lane * 65 + k];  // lane = s-row

  float mu = 0.f;
#pragma unroll
  for (int k = 0; k < 64; ++k) mu += x[k];
  mu *= (1.0f / 64.0f);
  float var = 0.f;
#pragma unroll
  for (int k = 0; k < 64; ++k) { const float d = x[k] - mu; var += d * d; }
  var *= (1.0f / 64.0f);
  const float rstd = rsqrtf(var + 1e-5f);
#pragma unroll
  for (int k = 0; k < 64; ++k)
    x[k] = (x[k] - mu) * rstd * gamma[k] + beta[k];

  const float mv = mask[(size_t)(s0 + lane) * NT + i];

  // ---- projection A ----
  float acc[32];
#pragma unroll
  for (int c = 0; c < 32; ++c) acc[c] = 0.f;
#pragma unroll 8
  for (int k = 0; k < 64; ++k) {
    const float mk = x[k];
#pragma unroll
    for (int c = 0; c < 32; ++c) acc[c] = fmaf(mk, Wa[k * 32 + c], acc[c]);
  }
  __syncthreads();  // fence: all fp32 tile reads complete before T overwrites it
#pragma unroll
  for (int c = 0; c < 32; ++c) T[c * 72 + lane] = (__bf16)(acc[c] * mv);
  __syncthreads();
  {
    // dest: rb=i>>2, r=(i&3)*32+c, kc = s0/8 + kc_loc, e = s&7
    __bf16* dst = Abf + (size_t)(i >> 2) * 65536 + (size_t)(s0 >> 3) * 1024 +
                  (size_t)((i & 3) * 32) * 8;
#pragma unroll
    for (int q = 0; q < 4; ++q) {
      const bf16x8 v = *(const bf16x8*)(T + l31 * 72 + (q * 2 + lh) * 8);
      *(bf16x8*)(dst + (size_t)(q * 2 + lh) * 1024 + l31 * 8) = v;
    }
  }
  __syncthreads();

  // ---- projection B ----
#pragma unroll
  for (int c = 0; c < 32; ++c) acc[c] = 0.f;
#pragma unroll 8
  for (int k = 0; k < 64; ++k) {
    const float mk = x[k];
#pragma unroll
    for (int c = 0; c < 32; ++c) acc[c] = fmaf(mk, Wb[k * 32 + c], acc[c]);
  }
#pragma unroll
  for (int c = 0; c < 32; ++c) T[c * 72 + lane] = (__bf16)(acc[c] * mv);
  __syncthreads();
  {
    __bf16* dst = Bbf + (size_t)(i >> 3) * 131072 + (size_t)(s0 >> 3) * 2048 +
                  (size_t)((i & 7) * 32) * 8;
#pragma unroll
    for (int q = 0; q < 4; ++q) {
      const bf16x8 v = *(const bf16x8*)(T + l31 * 72 + (q * 2 + lh) * 8);
      *(bf16x8*)(dst + (size_t)(q * 2 + lh) * 2048 + l31 * 8) = v;
    }
  }
}

// ---------------------------------------------------------------------------
// Fused GEMM. ROUND-6 CHANGE: same 128x256 block / 2-phase sync / traffic as
// r0 (the best-measured structure), but decomposed into 8 waves of 64x64
// (acc = 4x16 = 64 VGPR) instead of 4 waves of 64x128 (128 VGPR).
// __launch_bounds__(512,4) -> 2 blocks/CU = 4 waves/SIMD (was 2): the r0-r5
// plateau (MfmaUtil ~30-33% across ALL schedules) means ~70% of the time no
// resident wave has an MFMA ready; doubling independent streams per SIMD
// attacks that directly without r3's confounds (block count, WT duplication,
// bank conflicts all unchanged or better here).
// Riders: (a) epilogue waves own 16-wide e-slices -> WT reads/block halve
// (512->256 KB); (b) non-temporal out stores (75 MB of write-allocate was
// flooding the 4MB L2s; r4/r5 FETCH showed B never became L2-resident).
// Grid 96x48 bm-major (r0-proven: XCD=bm%8, A L2-resident, FETCH ~115 MB).
// ---------------------------------------------------------------------------
__global__ __launch_bounds__(512, 4) void opm_gemm(const __bf16* __restrict__ A,
                                                   const __bf16* __restrict__ B,
                                                   const __bf16* __restrict__ WT,
                                                   const float* __restrict__ bout,
                                                   const float* __restrict__ rnorm,
                                                   float* __restrict__ out) {
  __shared__ __align__(16) __bf16 smem[24576];  // 49152 B
  // buffer b: As = smem + b*12288 (4 kc x 128 r x 8 e), Bs = As + 4096 (4x256x8)
  // epilogue alias: P[p][d][c'] at p*648 + d*20 + c', p<32 (20736 elems)

  const int tid = threadIdx.x, lane = tid & 63, wid = tid >> 6;
  const int wm = wid & 1, wn = wid >> 1;         // 2 x 4 wave grid, wave 64x64
  const int l31 = lane & 31, lh = lane >> 5;
  const int l15 = lane & 15, lq = lane >> 4;     // epilogue 16x16 indexing
  const int bm = blockIdx.x % 96, bn = blockIdx.x / 96;

  const __bf16* Apan = A + (size_t)bm * 65536;
  const __bf16* Bpan = B + (size_t)bn * 131072;

  floatx16 acc[2][2];
#pragma unroll
  for (int fm = 0; fm < 2; ++fm)
#pragma unroll
    for (int fn = 0; fn < 2; ++fn)
#pragma unroll
      for (int q = 0; q < 16; ++q) acc[fm][fn][q] = 0.f;

  // Staging: 24 KB/kt. A chunk 4096 elems: wave w loads 512 elems (1 inst).
  // B chunk 8192 elems: wave w loads chunks q*8+w (2 insts). 3 insts/wave.
#define STAGE(kt, OFF)                                                          \
  {                                                                             \
    __bf16* dst = smem + (OFF);                                                 \
    __builtin_amdgcn_global_load_lds(                                           \
        (const __attribute__((address_space(1))) void*)(Apan +                  \
            (size_t)(kt) * 4096 + wid * 512 + lane * 8),                        \
        (__attribute__((address_space(3))) void*)(dst + wid * 512), 16, 0, 0);  \
    _Pragma("unroll")                                                           \
    for (int q = 0; q < 2; ++q) {                                               \
      const int g = q * 8 + wid;                                                \
      __builtin_amdgcn_global_load_lds(                                         \
          (const __attribute__((address_space(1))) void*)(Bpan +                \
              (size_t)(kt) * 8192 + g * 512 + lane * 8),                        \
          (__attribute__((address_space(3))) void*)(dst + 4096 + g * 512),      \
          16, 0, 0);                                                            \
    }                                                                           \
  }

  STAGE(0, 0);
  int buf = 0;
  for (int kt = 0; kt < 16; ++kt) {
    __syncthreads();                    // drains stage loads of buf
    if (kt < 15) STAGE(kt + 1, (buf ^ 1) * 12288);
    const __bf16* As = smem + buf * 12288;
    const __bf16* Bs = As + 4096;
    __builtin_amdgcn_s_setprio(1);
#pragma unroll
    for (int ks = 0; ks < 2; ++ks) {
      const int ck = ks * 2 + lh;
      bf16x8 af[2], bfv[2];
#pragma unroll
      for (int fm = 0; fm < 2; ++fm)
        af[fm] = *(const bf16x8*)(As + ck * 1024 + (wm * 64 + fm * 32 + l31) * 8);
#pragma unroll
      for (int fn = 0; fn < 2; ++fn)
        bfv[fn] = *(const bf16x8*)(Bs + ck * 2048 + (wn * 64 + fn * 32 + l31) * 8);
#pragma unroll
      for (int fm = 0; fm < 2; ++fm)
#pragma unroll
        for (int fn = 0; fn < 2; ++fn)
          acc[fm][fn] = __builtin_amdgcn_mfma_f32_32x32x16_bf16(af[fm], bfv[fn],
                                                                acc[fm][fn], 0, 0, 0);
    }
    __builtin_amdgcn_s_setprio(0);
    buf ^= 1;
  }
#undef STAGE

  // ---- epilogue: 2 rounds over c-halves, z accumulates over rounds ----
  // Wave owns e-slice [wid*16, +16) and ALL 32 p rows (2 p-frags).
  floatx4 zf[2];
#pragma unroll
  for (int ps = 0; ps < 2; ++ps)
#pragma unroll
    for (int q = 0; q < 4; ++q) zf[ps][q] = 0.f;
  const int e0 = wid * 16;

#pragma unroll
  for (int round = 0; round < 2; ++round) {
    __syncthreads();  // main-loop reads / previous GEMM2 reads complete
    // scatter: p = (wm*2+fm)*8 + wn*2+fn; P[p][d=l31][c'], d-stride 20,
    // c' = 8*qp + 4*lh + j  (c = 16*round + c', acc reg = round*8+qp*4+j)
#pragma unroll
    for (int fm = 0; fm < 2; ++fm)
#pragma unroll
      for (int fn = 0; fn < 2; ++fn) {
        const int p = (wm * 2 + fm) * 8 + wn * 2 + fn;
        __bf16* base = smem + p * 648 + l31 * 20 + lh * 4;
#pragma unroll
        for (int qp = 0; qp < 2; ++qp) {
          bf16x4 v;
#pragma unroll
          for (int j = 0; j < 4; ++j)
            v[j] = (__bf16)acc[fm][fn][round * 8 + qp * 4 + j];
          *(bf16x4*)(base + qp * 8) = v;
        }
      }
    __syncthreads();
    // GEMM2 (16x16x32): z[p][e] += P[p][k] * WT[e][round*512+k], K=512.
    // k = ks*32 + lq*8: P addr = row*648 + ks*40 + (lq>>1)*20 + (lq&1)*8.
    const int pAddr = (lq >> 1) * 20 + (lq & 1) * 8;
    const __bf16* p0 = smem + l15 * 648 + pAddr;
    const __bf16* p1 = p0 + 16 * 648;
    const __bf16* w0 = WT + (size_t)(e0 + l15) * 1024 + round * 512 + lq * 8;
#pragma unroll 4
    for (int ks = 0; ks < 16; ++ks) {
      const bf16x8 pa0 = *(const bf16x8*)(p0 + ks * 40);
      const bf16x8 pa1 = *(const bf16x8*)(p1 + ks * 40);
      const bf16x8 wb = *(const bf16x8*)(w0 + ks * 32);
      zf[0] = __builtin_amdgcn_mfma_f32_16x16x32_bf16(pa0, wb, zf[0], 0, 0, 0);
      zf[1] = __builtin_amdgcn_mfma_f32_16x16x32_bf16(pa1, wb, zf[1], 0, 0, 0);
    }
  }

  // out[i][j][e] = (z + bout[e]) * rnorm[i][j]; D-frag: row p = ps*16+lq*4+q,
  // col e = e0 + l15. Non-temporal stores: don't allocate 75 MB in L2.
  {
    const int e = e0 + l15;
    const float be = bout[e];
#pragma unroll
    for (int ps = 0; ps < 2; ++ps)
#pragma unroll
      for (int q = 0; q < 4; ++q) {
        const int p = ps * 16 + lq * 4 + q;
        const int i = bm * 4 + (p >> 3), j = bn * 8 + (p & 7);
        const float rn = rnorm[(size_t)i * NT + j];
        __builtin_nontemporal_store((zf[ps][q] + be) * rn,
                                    out + ((size_t)i * NT + j) * CZ + e);
      }
  }
}

// ---------------------------------------------------------------------------
extern "C" void kernel_launch(void* const* d_in, const int* in_sizes, int n_in,
                              void* d_out, int out_size, void* d_ws, size_t ws_size,
                              hipStream_t stream) {
  const float* feat  = (const float*)d_in[0];
  const float* mask  = (const float*)d_in[1];
  const float* gamma = (const float*)d_in[2];
  const float* beta  = (const float*)d_in[3];
  const float* Wa    = (const float*)d_in[4];
  const float* Wb    = (const float*)d_in[5];
  const float* Wout  = (const float*)d_in[6];
  const float* bout  = (const float*)d_in[7];
  float* out = (float*)d_out;

  char* ws = (char*)d_ws;
  const size_t AB_BYTES = (size_t)96 * 65536 * sizeof(__bf16);  // 12,582,912
  __bf16* Abf = (__bf16*)(ws);
  __bf16* Bbf = (__bf16*)(ws + AB_BYTES);
  __bf16* WT  = (__bf16*)(ws + 2 * AB_BYTES);
  float* rnorm = (float*)(ws + 2 * AB_BYTES + (size_t)CZ * 1024 * sizeof(__bf16));

  prep_wout<<<512, 256, 0, stream>>>(Wout, WT);
  prep_norm<<<NT, 256, 0, stream>>>(mask, rnorm);
  ln_proj<<<NT * (NS / 64), 64, 0, stream>>>(feat, mask, gamma, beta, Wa, Wb, Abf, Bbf);
  opm_gemm<<<96 * 48, 512, 0, stream>>>(Abf, Bbf, WT, bout, rnorm, out);
}